// Round 10
// baseline (320.209 us; speedup 1.0000x reference)
//
#include <hip/hip_runtime.h>

#define D 64
#define BLK 256

#define NBSHIFT 9
#define NODES_PER_BKT 512              // bucket = row >> 9; NB <= 256 for N <= 131072
#define TA 4096                        // edges per binA tile

typedef unsigned int uint32;
typedef __attribute__((ext_vector_type(8))) short bf16x8;
typedef __attribute__((ext_vector_type(4))) float f32x4;

// ---- bf16 helpers (RTNE) ----
__device__ inline uint32 f2bf_u(float f) {
    uint32 u = __float_as_uint(f);
    u += 0x7FFFu + ((u >> 16) & 1u);
    return u >> 16;
}

// ---------------- fused prep: hist | cvt | wf ----------------
// blocks [0, gTile): bucket histogram; [gTile, gTile+gCvt): x->bf16; last 8: W pack.
// Wf chunk layout: Wf[(w*8 + t*2 + kh)*64 + lane], chunks w: 0=W0, 1=W1-W3, 2=W2, 3=W3.
__global__ void prep_kernel(const int* __restrict__ row, uint32* __restrict__ bcount,
                            const float* __restrict__ x, uint2* __restrict__ xb,
                            const float* __restrict__ W, uint4* __restrict__ Wf,
                            int E, int n4, int gTile, int gCvt) {
    int bid = blockIdx.x;
    int tid = threadIdx.x;
    if (bid < gTile) {
        __shared__ uint32 h[256];
        h[tid] = 0;
        __syncthreads();
        int base = bid * TA;
        int end = min(base + TA, E);
        for (int e = base + tid; e < end; e += 256)
            atomicAdd(&h[(uint32)row[e] >> NBSHIFT], 1u);
        __syncthreads();
        if (h[tid]) atomicAdd(&bcount[tid], h[tid]);
    } else if (bid < gTile + gCvt) {
        int i = (bid - gTile) * 256 + tid;
        if (i < n4) {
            float4 v = ((const float4*)x)[i];
            uint2 pack;
            pack.x = f2bf_u(v.x) | (f2bf_u(v.y) << 16);
            pack.y = f2bf_u(v.z) | (f2bf_u(v.w) << 16);
            xb[i] = pack;
        }
    } else {
        int t2 = (bid - gTile - gCvt) * 256 + tid;   // 0..2047
        int l = t2 & 63;
        int g = t2 >> 6;       // 0..31
        int kh = g & 1;
        int t = (g >> 1) & 3;
        int w = g >> 3;
        int n = t * 16 + (l & 15);
        int kbase = kh * 32 + (l >> 4) * 8;
        uint32 pk[4];
        #pragma unroll
        for (int i = 0; i < 4; ++i) {
            #pragma unroll
            for (int h2 = 0; h2 < 1; ++h2) {}
            int k0 = kbase + 2 * i, k1 = k0 + 1;
            float v0, v1;
            if (w == 1) {
                v0 = W[4096 + (size_t)k0 * 64 + n] - W[3 * 4096 + (size_t)k0 * 64 + n];
                v1 = W[4096 + (size_t)k1 * 64 + n] - W[3 * 4096 + (size_t)k1 * 64 + n];
            } else {
                int ws = (w == 0) ? 0 : (w == 2) ? 2 : 3;
                v0 = W[(size_t)ws * 4096 + (size_t)k0 * 64 + n];
                v1 = W[(size_t)ws * 4096 + (size_t)k1 * 64 + n];
            }
            pk[i] = f2bf_u(v0) | (f2bf_u(v1) << 16);
        }
        Wf[t2] = make_uint4(pk[0], pk[1], pk[2], pk[3]);
    }
}

// ---------------- scan of 256 bucket counts -> gcursor (mutable) + bbase (stable) ----------------
__global__ void scan256_kernel(const uint32* __restrict__ bcount, uint32* __restrict__ gcursor,
                               uint32* __restrict__ bbase, int E) {
    __shared__ uint32 s[256];
    int tid = threadIdx.x;
    uint32 v = bcount[tid];
    s[tid] = v;
    __syncthreads();
    for (int off = 1; off < 256; off <<= 1) {
        uint32 t = (tid >= off) ? s[tid - off] : 0u;
        __syncthreads();
        s[tid] += t;
        __syncthreads();
    }
    uint32 excl = s[tid] - v;
    gcursor[tid] = excl;
    bbase[tid] = excl;
    if (tid == 255) bbase[256] = (uint32)E;
}

// ---------------- pass A: bin (rowlocal<<17|col, attr) by bucket, LDS-staged run writes ----------------
__global__ void binA_kernel(const int* __restrict__ row, const int* __restrict__ col,
                            const float* __restrict__ attr,
                            uint32* __restrict__ gcursor, int2* __restrict__ binned, int E) {
    __shared__ uint32 hist[256], baseg[256], lstart[256], lcur[256];
    __shared__ int2 stage[TA];
    __shared__ unsigned char sbkt[TA];
    int tid = threadIdx.x;
    int tile = blockIdx.x * TA;
    hist[tid] = 0;
    __syncthreads();

    uint32 px[16], py[16], bk[16];
    #pragma unroll
    for (int k = 0; k < 16; ++k) {
        int e = tile + k * 256 + tid;
        bk[k] = 0xFFFFFFFFu;
        if (e < E) {
            int r = row[e], c = col[e];
            uint32 b = (uint32)r >> NBSHIFT;
            bk[k] = b;
            px[k] = ((uint32)(r & (NODES_PER_BKT - 1)) << 17) | (uint32)c;
            py[k] = __float_as_uint(attr[e]);
            atomicAdd(&hist[b], 1u);
        }
    }
    __syncthreads();
    lcur[tid] = hist[tid];
    __syncthreads();
    for (int off = 1; off < 256; off <<= 1) {
        uint32 t = (tid >= off) ? lcur[tid - off] : 0u;
        __syncthreads();
        lcur[tid] += t;
        __syncthreads();
    }
    lstart[tid] = lcur[tid] - hist[tid];
    if (hist[tid] > 0) baseg[tid] = atomicAdd(&gcursor[tid], hist[tid]);
    lcur[tid] = lstart[tid];
    __syncthreads();
    #pragma unroll
    for (int k = 0; k < 16; ++k) {
        if (bk[k] != 0xFFFFFFFFu) {
            uint32 pos = atomicAdd(&lcur[bk[k]], 1u);
            stage[pos] = make_int2((int)px[k], (int)py[k]);
            sbkt[pos] = (unsigned char)bk[k];
        }
    }
    __syncthreads();
    int cnt = min(TA, E - tile);
    for (int i = tid; i < cnt; i += 256) {
        uint32 b = sbkt[i];
        uint32 dst = baseg[b] + (uint32)i - lstart[b];
        binned[dst] = stage[i];
    }
}

// ---------------- fused pass B: degree count + scan -> rowptr/dinv; sort -> pairs; gx = dinv (.) xb ----------------
// pairs.y = -dinv[row]*attr (NO foreign dinv needed -> single kernel).
__global__ void binB_kernel(const int2* __restrict__ binned, const uint32* __restrict__ bbase,
                            uint32* __restrict__ rowptr, float* __restrict__ dinv,
                            int2* __restrict__ pairs,
                            const uint2* __restrict__ xb, uint2* __restrict__ gx,
                            int N, int E, int lastB) {
    __shared__ uint32 cnt[NODES_PER_BKT];
    __shared__ uint32 ps[256];
    __shared__ uint32 lcur[NODES_PER_BKT];
    __shared__ float ldin[NODES_PER_BKT];
    int b = blockIdx.x;
    int tid = threadIdx.x;
    int base = b << NBSHIFT;
    uint32 start = bbase[b], end = bbase[b + 1];
    cnt[tid] = 0;
    cnt[tid + 256] = 0;
    __syncthreads();
    for (uint32 i = start + tid; i < end; i += 256)
        atomicAdd(&cnt[(uint32)binned[i].x >> 17], 1u);
    __syncthreads();
    uint32 c0 = cnt[2 * tid], c1 = cnt[2 * tid + 1];
    ps[tid] = c0 + c1;
    __syncthreads();
    for (int off = 1; off < 256; off <<= 1) {
        uint32 t = (tid >= off) ? ps[tid - off] : 0u;
        __syncthreads();
        ps[tid] += t;
        __syncthreads();
    }
    uint32 pexcl = ps[tid] - (c0 + c1);
    float d0 = c0 ? rsqrtf((float)c0) : 0.0f;
    float d1 = c1 ? rsqrtf((float)c1) : 0.0f;
    lcur[2 * tid] = pexcl;
    lcur[2 * tid + 1] = pexcl + c0;
    ldin[2 * tid] = d0;
    ldin[2 * tid + 1] = d1;
    int n0 = base + 2 * tid, n1 = n0 + 1;
    if (n0 < N) { rowptr[n0] = start + pexcl;      dinv[n0] = d0; }
    if (n1 < N) { rowptr[n1] = start + pexcl + c0; dinv[n1] = d1; }
    if (b == lastB && tid == 0) rowptr[N] = (uint32)E;
    __syncthreads();
    // sort pass: pairs = (col<<7, -dinv_row*attr)
    for (uint32 i = start + tid; i < end; i += 256) {
        int2 rec = binned[i];
        uint32 xx = (uint32)rec.x;
        uint32 rl = xx >> 17;
        uint32 c = xx & 0x1FFFFu;
        float y = -ldin[rl] * __int_as_float(rec.y);
        uint32 pos = atomicAdd(&lcur[rl], 1u);
        pairs[start + pos] = make_int2((int)(c << 7), __float_as_int(y));
    }
    // gx pass: prescale this bucket's xb rows by dinv (coalesced)
    for (int i = tid; i < NODES_PER_BKT * 16; i += 256) {
        int r = i >> 4;
        int node = base + r;
        if (node >= N) break;
        uint2 v = xb[(size_t)node * 16 + (i & 15)];
        float s = ldin[r];
        float f0 = __uint_as_float(v.x << 16) * s;
        float f1 = __uint_as_float(v.x & 0xFFFF0000u) * s;
        float f2 = __uint_as_float(v.y << 16) * s;
        float f3 = __uint_as_float(v.y & 0xFFFF0000u) * s;
        uint2 o;
        o.x = f2bf_u(f0) | (f2bf_u(f1) << 16);
        o.y = f2bf_u(f2) | (f2bf_u(f3) << 16);
        gx[(size_t)node * 16 + (i & 15)] = o;
    }
}

// ---------------- CSR SpMM (T-producing): out = bf16(scale*acc - prev); optional g-out = bf16(dinv*out) ----------------
__global__ void spmm_t_kernel(const uint32* __restrict__ rowptr, const int2* __restrict__ pairs,
                              const char* __restrict__ gin, const uint4* __restrict__ prev,
                              uint4* __restrict__ outT, uint4* __restrict__ outG,
                              const float* __restrict__ dinv, float scale, int N) {
    int n = blockIdx.x * 4 + (threadIdx.x >> 6);
    if (n >= N) return;
    int lane = threadIdx.x & 63;
    int q = lane >> 3;
    int sub = lane & 7;
    int off = sub * 16;
    uint32 j = rowptr[n];
    uint32 end = rowptr[n + 1];
    float a[8];
    #pragma unroll
    for (int i = 0; i < 8; ++i) a[i] = 0.0f;

    for (; j + 16 <= end; j += 16) {
        int2 m0 = pairs[j + q];
        int2 m1 = pairs[j + 8 + q];
        uint4 h0 = *(const uint4*)(gin + (uint32)m0.x + off);
        uint4 h1 = *(const uint4*)(gin + (uint32)m1.x + off);
        float l0 = __int_as_float(m0.y);
        float l1 = __int_as_float(m1.y);
        a[0] += l0 * __uint_as_float(h0.x << 16);
        a[1] += l0 * __uint_as_float(h0.x & 0xFFFF0000u);
        a[2] += l0 * __uint_as_float(h0.y << 16);
        a[3] += l0 * __uint_as_float(h0.y & 0xFFFF0000u);
        a[4] += l0 * __uint_as_float(h0.z << 16);
        a[5] += l0 * __uint_as_float(h0.z & 0xFFFF0000u);
        a[6] += l0 * __uint_as_float(h0.w << 16);
        a[7] += l0 * __uint_as_float(h0.w & 0xFFFF0000u);
        a[0] += l1 * __uint_as_float(h1.x << 16);
        a[1] += l1 * __uint_as_float(h1.x & 0xFFFF0000u);
        a[2] += l1 * __uint_as_float(h1.y << 16);
        a[3] += l1 * __uint_as_float(h1.y & 0xFFFF0000u);
        a[4] += l1 * __uint_as_float(h1.z << 16);
        a[5] += l1 * __uint_as_float(h1.z & 0xFFFF0000u);
        a[6] += l1 * __uint_as_float(h1.w << 16);
        a[7] += l1 * __uint_as_float(h1.w & 0xFFFF0000u);
    }
    for (; j < end; j += 8) {
        uint32 idx = j + q;
        bool act = idx < end;
        uint32 ci = act ? idx : (end - 1);
        int2 m = pairs[ci];
        float l = act ? __int_as_float(m.y) : 0.0f;
        uint4 h0 = *(const uint4*)(gin + (uint32)m.x + off);
        a[0] += l * __uint_as_float(h0.x << 16);
        a[1] += l * __uint_as_float(h0.x & 0xFFFF0000u);
        a[2] += l * __uint_as_float(h0.y << 16);
        a[3] += l * __uint_as_float(h0.y & 0xFFFF0000u);
        a[4] += l * __uint_as_float(h0.z << 16);
        a[5] += l * __uint_as_float(h0.z & 0xFFFF0000u);
        a[6] += l * __uint_as_float(h0.w << 16);
        a[7] += l * __uint_as_float(h0.w & 0xFFFF0000u);
    }
    #pragma unroll
    for (int i = 0; i < 8; ++i) {
        a[i] += __shfl_xor(a[i], 8);
        a[i] += __shfl_xor(a[i], 16);
        a[i] += __shfl_xor(a[i], 32);
    }

    if (q == 0) {
        float r[8];
        #pragma unroll
        for (int i = 0; i < 8; ++i) r[i] = scale * a[i];
        size_t slot = (size_t)n * 8 + sub;
        if (prev) {
            uint4 pv = prev[slot];
            r[0] -= __uint_as_float(pv.x << 16);
            r[1] -= __uint_as_float(pv.x & 0xFFFF0000u);
            r[2] -= __uint_as_float(pv.y << 16);
            r[3] -= __uint_as_float(pv.y & 0xFFFF0000u);
            r[4] -= __uint_as_float(pv.z << 16);
            r[5] -= __uint_as_float(pv.z & 0xFFFF0000u);
            r[6] -= __uint_as_float(pv.w << 16);
            r[7] -= __uint_as_float(pv.w & 0xFFFF0000u);
        }
        uint4 pack;
        pack.x = f2bf_u(r[0]) | (f2bf_u(r[1]) << 16);
        pack.y = f2bf_u(r[2]) | (f2bf_u(r[3]) << 16);
        pack.z = f2bf_u(r[4]) | (f2bf_u(r[5]) << 16);
        pack.w = f2bf_u(r[6]) | (f2bf_u(r[7]) << 16);
        outT[slot] = pack;
        if (outG) {
            float dn = dinv[n];
            uint4 pg;
            pg.x = f2bf_u(r[0] * dn) | (f2bf_u(r[1] * dn) << 16);
            pg.y = f2bf_u(r[2] * dn) | (f2bf_u(r[3] * dn) << 16);
            pg.z = f2bf_u(r[4] * dn) | (f2bf_u(r[5] * dn) << 16);
            pg.w = f2bf_u(r[6] * dn) | (f2bf_u(r[7] * dn) << 16);
            outG[slot] = pg;
        }
    }
}

// ---------------- final SpMM: out(fp32) += 2 * sum pairs.y * gU[col] ----------------
__global__ void spmm_f_kernel(const uint32* __restrict__ rowptr, const int2* __restrict__ pairs,
                              const char* __restrict__ gin, float* __restrict__ out, int N) {
    int n = blockIdx.x * 4 + (threadIdx.x >> 6);
    if (n >= N) return;
    int lane = threadIdx.x & 63;
    int q = lane >> 3;
    int sub = lane & 7;
    int off = sub * 16;
    uint32 j = rowptr[n];
    uint32 end = rowptr[n + 1];
    float a[8];
    #pragma unroll
    for (int i = 0; i < 8; ++i) a[i] = 0.0f;

    for (; j + 16 <= end; j += 16) {
        int2 m0 = pairs[j + q];
        int2 m1 = pairs[j + 8 + q];
        uint4 h0 = *(const uint4*)(gin + (uint32)m0.x + off);
        uint4 h1 = *(const uint4*)(gin + (uint32)m1.x + off);
        float l0 = __int_as_float(m0.y);
        float l1 = __int_as_float(m1.y);
        a[0] += l0 * __uint_as_float(h0.x << 16);
        a[1] += l0 * __uint_as_float(h0.x & 0xFFFF0000u);
        a[2] += l0 * __uint_as_float(h0.y << 16);
        a[3] += l0 * __uint_as_float(h0.y & 0xFFFF0000u);
        a[4] += l0 * __uint_as_float(h0.z << 16);
        a[5] += l0 * __uint_as_float(h0.z & 0xFFFF0000u);
        a[6] += l0 * __uint_as_float(h0.w << 16);
        a[7] += l0 * __uint_as_float(h0.w & 0xFFFF0000u);
        a[0] += l1 * __uint_as_float(h1.x << 16);
        a[1] += l1 * __uint_as_float(h1.x & 0xFFFF0000u);
        a[2] += l1 * __uint_as_float(h1.y << 16);
        a[3] += l1 * __uint_as_float(h1.y & 0xFFFF0000u);
        a[4] += l1 * __uint_as_float(h1.z << 16);
        a[5] += l1 * __uint_as_float(h1.z & 0xFFFF0000u);
        a[6] += l1 * __uint_as_float(h1.w << 16);
        a[7] += l1 * __uint_as_float(h1.w & 0xFFFF0000u);
    }
    for (; j < end; j += 8) {
        uint32 idx = j + q;
        bool act = idx < end;
        uint32 ci = act ? idx : (end - 1);
        int2 m = pairs[ci];
        float l = act ? __int_as_float(m.y) : 0.0f;
        uint4 h0 = *(const uint4*)(gin + (uint32)m.x + off);
        a[0] += l * __uint_as_float(h0.x << 16);
        a[1] += l * __uint_as_float(h0.x & 0xFFFF0000u);
        a[2] += l * __uint_as_float(h0.y << 16);
        a[3] += l * __uint_as_float(h0.y & 0xFFFF0000u);
        a[4] += l * __uint_as_float(h0.z << 16);
        a[5] += l * __uint_as_float(h0.z & 0xFFFF0000u);
        a[6] += l * __uint_as_float(h0.w << 16);
        a[7] += l * __uint_as_float(h0.w & 0xFFFF0000u);
    }
    #pragma unroll
    for (int i = 0; i < 8; ++i) {
        a[i] += __shfl_xor(a[i], 8);
        a[i] += __shfl_xor(a[i], 16);
        a[i] += __shfl_xor(a[i], 32);
    }

    if (q == 0) {
        float* basep = out + (size_t)n * 64 + sub * 8;
        float4 o0 = *(float4*)basep;
        float4 o1 = *(float4*)(basep + 4);
        o0.x += 2.0f * a[0]; o0.y += 2.0f * a[1]; o0.z += 2.0f * a[2]; o0.w += 2.0f * a[3];
        o1.x += 2.0f * a[4]; o1.y += 2.0f * a[5]; o1.z += 2.0f * a[6]; o1.w += 2.0f * a[7];
        *(float4*)basep = o0;
        *(float4*)(basep + 4) = o1;
    }
}

// ---------------- MFMA GEMM: out_base = bias + x@W0 + T1@(W1-W3) + T2@W2 ; gU = dinv (.) (T2@W3) ----------------
__global__ void gemm_mfma(const uint4* __restrict__ h0, const uint4* __restrict__ h1,
                          const uint4* __restrict__ h2,
                          const uint4* __restrict__ Wf, const float* __restrict__ bias,
                          const float* __restrict__ dinv,
                          float* __restrict__ out, unsigned short* __restrict__ gU, int N) {
    int tid = threadIdx.x;
    int wave = tid >> 6;
    int lane = tid & 63;
    int quad = lane >> 4;
    int lo = lane & 15;
    int m0 = blockIdx.x * 64 + wave * 16;
    int mrow = m0 + lo;
    int mclamp = min(mrow, N - 1);

    f32x4 acc[4] = {{0.f,0.f,0.f,0.f},{0.f,0.f,0.f,0.f},{0.f,0.f,0.f,0.f},{0.f,0.f,0.f,0.f}};
    f32x4 accU[4] = {{0.f,0.f,0.f,0.f},{0.f,0.f,0.f,0.f},{0.f,0.f,0.f,0.f},{0.f,0.f,0.f,0.f}};
    const uint4* hs[3] = { h0, h1, h2 };
    #pragma unroll
    for (int w = 0; w < 3; ++w) {
        union { uint4 u; bf16x8 v; } a0, a1;
        a0.u = hs[w][(size_t)mclamp * 8 + quad];       // kh = 0
        a1.u = hs[w][(size_t)mclamp * 8 + 4 + quad];   // kh = 1
        #pragma unroll
        for (int t = 0; t < 4; ++t) {
            union { uint4 u; bf16x8 v; } b0, b1;
            b0.u = Wf[(w * 8 + t * 2 + 0) * 64 + lane];
            b1.u = Wf[(w * 8 + t * 2 + 1) * 64 + lane];
            acc[t] = __builtin_amdgcn_mfma_f32_16x16x32_bf16(a0.v, b0.v, acc[t], 0, 0, 0);
            acc[t] = __builtin_amdgcn_mfma_f32_16x16x32_bf16(a1.v, b1.v, acc[t], 0, 0, 0);
        }
        if (w == 2) {
            #pragma unroll
            for (int t = 0; t < 4; ++t) {
                union { uint4 u; bf16x8 v; } b0, b1;
                b0.u = Wf[(3 * 8 + t * 2 + 0) * 64 + lane];
                b1.u = Wf[(3 * 8 + t * 2 + 1) * 64 + lane];
                accU[t] = __builtin_amdgcn_mfma_f32_16x16x32_bf16(a0.v, b0.v, accU[t], 0, 0, 0);
                accU[t] = __builtin_amdgcn_mfma_f32_16x16x32_bf16(a1.v, b1.v, accU[t], 0, 0, 0);
            }
        }
    }
    #pragma unroll
    for (int t = 0; t < 4; ++t) {
        int col = t * 16 + lo;
        float bv = bias[col];
        #pragma unroll
        for (int r = 0; r < 4; ++r) {
            int rowi = m0 + quad * 4 + r;
            if (rowi < N) {
                out[(size_t)rowi * 64 + col] = acc[t][r] + bv;
                float dn = dinv[rowi];
                gU[(size_t)rowi * 64 + col] = (unsigned short)f2bf_u(accU[t][r] * dn);
            }
        }
    }
}

extern "C" void kernel_launch(void* const* d_in, const int* in_sizes, int n_in,
                              void* d_out, int out_size, void* d_ws, size_t ws_size,
                              hipStream_t stream) {
    const float* x    = (const float*)d_in[0];
    const int*   ei   = (const int*)d_in[1];
    const float* attr = (const float*)d_in[2];
    const float* W    = (const float*)d_in[3];   // [4,64,64]
    const float* bias = (const float*)d_in[4];   // [64]
    float* out = (float*)d_out;

    const int N = in_sizes[0] / D;
    const int E = in_sizes[1] / 2;
    const int* row = ei;        // edge_index[0]
    const int* col = ei + E;    // edge_index[1]
    const int NB = (N + NODES_PER_BKT - 1) >> NBSHIFT;

    // workspace layout — 16B-aligned arrays first (~78 MB)
    char* p = (char*)d_ws;
    int2*     pairs   = (int2*)p;                p += (size_t)E * 8;
    uint2*    xb      = (uint2*)p;               p += (size_t)N * D * 2;
    uint2*    gx      = (uint2*)p;               p += (size_t)N * D * 2;  // reused as gU after spmm1
    uint2*    g1      = (uint2*)p;               p += (size_t)N * D * 2;
    uint2*    T1      = (uint2*)p;               p += (size_t)N * D * 2;  // aliases binned
    uint2*    T2      = (uint2*)p;               p += (size_t)N * D * 2;
    uint4*    Wf      = (uint4*)p;               p += 2048 * 16;
    uint32*   rowptr  = (uint32*)p;              p += (size_t)(N + 1) * 4;
    uint32*   bcount  = (uint32*)p;              p += 256 * 4;
    uint32*   gcursor = (uint32*)p;              p += 256 * 4;
    uint32*   bbase   = (uint32*)p;              p += 257 * 4;
    float*    dinv    = (float*)p;               /* p += N*4 */
    int2*     binned  = (int2*)T1;               // consumed by binB before spmm1 writes T1
    uint2*    gU      = gx;                      // gx dead after spmm1

    const int gSp = (N + 3) / 4;
    const int gGm = (N + 63) / 64;
    const int gTile = (E + TA - 1) / TA;
    const int gCvt = ((N * D / 4) + 255) / 256;

    // ---- prep (hist|cvt|wf) + CSR build ----
    hipMemsetAsync(bcount, 0, 256 * 4, stream);
    prep_kernel<<<gTile + gCvt + 8, 256, 0, stream>>>(row, bcount, x, xb, W, Wf,
                                                      E, N * D / 4, gTile, gCvt);
    scan256_kernel<<<1, 256, 0, stream>>>(bcount, gcursor, bbase, E);
    binA_kernel<<<gTile, 256, 0, stream>>>(row, col, attr, gcursor, binned, E);
    binB_kernel<<<NB, 256, 0, stream>>>(binned, bbase, rowptr, dinv, pairs, xb, gx, N, E, NB - 1);

    // ---- Chebyshev (g-scheme: gather prescaled rows; pairs.y = -dinv_row*attr) ----
    // T1 = S(x);  g1 = dinv(.)T1
    spmm_t_kernel<<<gSp, BLK, 0, stream>>>(rowptr, pairs, (const char*)gx, nullptr,
                                           (uint4*)T1, (uint4*)g1, dinv, 1.0f, N);
    // T2 = 2*S(T1) - x  (plain only)
    spmm_t_kernel<<<gSp, BLK, 0, stream>>>(rowptr, pairs, (const char*)g1, (const uint4*)xb,
                                           (uint4*)T2, nullptr, dinv, 2.0f, N);
    // out_base = bias + x@W0 + T1@(W1-W3) + T2@W2 ; gU = dinv(.)(T2@W3)
    gemm_mfma<<<gGm, BLK, 0, stream>>>((const uint4*)xb, (const uint4*)T1, (const uint4*)T2,
                                       Wf, bias, dinv, out, (unsigned short*)gU, N);
    // out += 2*S(U)   (T3@W3 = 2*S(T2@W3) - T1@W3, with -T1@W3 folded into W1')
    spmm_f_kernel<<<gSp, BLK, 0, stream>>>(rowptr, pairs, (const char*)gU, out, N);
}